// Round 7
// baseline (468.616 us; speedup 1.0000x reference)
//
#include <hip/hip_runtime.h>
#include <hip/hip_bf16.h>

#define N_NODES 100000
#define N_EDGES 600000
#define NB      512
#define H       128
#define ED      8
#define SCAN_CHUNK 1024
#define N_CHUNKS   98   // 98*1024 = 100352 >= N_NODES+1

typedef __attribute__((ext_vector_type(8))) short short8;
typedef __attribute__((ext_vector_type(4))) float f32x4;
typedef unsigned short u16;
typedef unsigned int   u32;

static __device__ __forceinline__ u16 f2bf(float f) {
    u32 u = __float_as_uint(f);
    u32 r = u + 0x7fffu + ((u >> 16) & 1u);
    return (u16)(r >> 16);
}
static __device__ __forceinline__ float bf2f(u32 h) {
    return __uint_as_float(h << 16);
}

// ---- weight pack (ALL matrices in one launch) -----------------------------
__global__ __launch_bounds__(256) void pack_all_kernel(
    const float* __restrict__ W0, const float* __restrict__ W1,
    const float* __restrict__ W2, const float* __restrict__ W3,
    const float* __restrict__ W4, const float* __restrict__ W5,
    const float* __restrict__ W6,
    short8* __restrict__ O0, short8* __restrict__ O1,
    short8* __restrict__ O2, short8* __restrict__ O3,
    short8* __restrict__ O4, short8* __restrict__ O5,
    short8* __restrict__ O6)
{
    int gid = blockIdx.x * 256 + threadIdx.x;
    const int total = 512 + 6 * 2048;
    if (gid >= total) return;
    const float* W; short8* O; int Krows, kkmax, slot;
    if (gid < 512) { W = W0; O = O0; Krows = ED; kkmax = 1; slot = gid; }
    else {
        int m = (gid - 512) / 2048;
        slot = (gid - 512) % 2048;
        Krows = H; kkmax = 4;
        switch (m) {
            case 0: W = W1; O = O1; break;
            case 1: W = W2; O = O2; break;
            case 2: W = W3; O = O3; break;
            case 3: W = W4; O = O4; break;
            case 4: W = W5; O = O5; break;
            default: W = W6; O = O6; break;
        }
    }
    int lane = slot & 63;
    int t = slot >> 6;
    int nt = t & 1; t >>= 1;
    int kk = t % kkmax;
    int w  = t / kkmax;
    int quad = lane >> 4, n15 = lane & 15;
    int n = w * 32 + nt * 16 + n15;
    short8 v;
    #pragma unroll
    for (int j = 0; j < 8; j++) {
        int k = kk * 32 + quad * 8 + j;
        v[j] = (k < Krows) ? (short)f2bf(W[k * H + n]) : (short)0;
    }
    O[slot] = v;
}

// ---------------- CSR build ------------------------------------------------
__global__ __launch_bounds__(256) void hist_kernel(
    const int* __restrict__ edge_index, int* __restrict__ counts)
{
    int e = blockIdx.x * 256 + threadIdx.x;
    if (e < N_EDGES) atomicAdd(&counts[edge_index[N_EDGES + e]], 1);
}

__global__ __launch_bounds__(SCAN_CHUNK) void scan1_kernel(
    const int* __restrict__ counts, int* __restrict__ chunk_scan,
    int* __restrict__ bsum_raw)
{
    __shared__ int s[SCAN_CHUNK];
    int tid = threadIdx.x;
    int gid = blockIdx.x * SCAN_CHUNK + tid;
    int v = counts[gid];
    s[tid] = v;
    __syncthreads();
    #pragma unroll
    for (int off = 1; off < SCAN_CHUNK; off <<= 1) {
        int t = (tid >= off) ? s[tid - off] : 0;
        __syncthreads();
        s[tid] += t;
        __syncthreads();
    }
    chunk_scan[gid] = s[tid] - v;
    if (tid == SCAN_CHUNK - 1) bsum_raw[blockIdx.x] = s[tid];
}

__global__ __launch_bounds__(128) void scan2_kernel(
    const int* __restrict__ bsum_raw, int* __restrict__ bsum_scan)
{
    __shared__ int s[128];
    int tid = threadIdx.x;
    int v = (tid < N_CHUNKS) ? bsum_raw[tid] : 0;
    s[tid] = v;
    __syncthreads();
    #pragma unroll
    for (int off = 1; off < 128; off <<= 1) {
        int t = (tid >= off) ? s[tid - off] : 0;
        __syncthreads();
        s[tid] += t;
        __syncthreads();
    }
    bsum_scan[tid] = s[tid] - v;
}

__global__ __launch_bounds__(256) void rowptr_kernel(
    const int* __restrict__ chunk_scan, const int* __restrict__ bsum_scan,
    int* __restrict__ row_ptr)
{
    int gid = blockIdx.x * 256 + threadIdx.x;
    if (gid <= N_NODES) row_ptr[gid] = chunk_scan[gid] + bsum_scan[gid >> 10];
}

__global__ __launch_bounds__(256) void fill_kernel(
    const int* __restrict__ edge_index,
    const int* __restrict__ chunk_scan, const int* __restrict__ bsum_scan,
    int* __restrict__ counts, int* __restrict__ src_list,
    int* __restrict__ pos_of)
{
    int e = blockIdx.x * 256 + threadIdx.x;
    if (e >= N_EDGES) return;
    int src = edge_index[e];
    int dst = edge_index[N_EDGES + e];
    int slot = atomicAdd(&counts[dst], -1) - 1;
    int pos = chunk_scan[dst] + bsum_scan[dst >> 10] + slot;
    src_list[pos] = src;
    pos_of[e] = pos;
}

// ---------------- node MLP (MFMA layer2): x bf16 [N,H] ---------------------
__global__ __launch_bounds__(256) void node_mlp_mfma(
    const int* __restrict__ ids,
    const float* __restrict__ w1, const float* __restrict__ b1,
    const short8* __restrict__ pW2, const float* __restrict__ b2,
    u16* __restrict__ x_out)
{
    __shared__ u16 sH[64 * 136];
    __shared__ float s_x0[64];
    int tid = threadIdx.x;
    int w = tid >> 6, lane = tid & 63, quad = lane >> 4, n15 = lane & 15;
    short8 fW2[4][2];
    #pragma unroll
    for (int kk = 0; kk < 4; kk++) {
        fW2[kk][0] = pW2[((w * 4 + kk) * 2 + 0) * 64 + lane];
        fW2[kk][1] = pW2[((w * 4 + kk) * 2 + 1) * 64 + lane];
    }
    float rb2[2] = { b2[w * 32 + n15], b2[w * 32 + 16 + n15] };
    float w1c = w1[tid & 127], b1c = b1[tid & 127];
    const int ntile = (N_NODES + 63) / 64;
    for (int tile = blockIdx.x; tile < ntile; tile += gridDim.x) {
        int row0 = tile * 64;
        if (tid < 64) {
            int n = row0 + tid;
            float x0 = (n < N_NODES) ? (float)ids[n] / 281474976710655.0f : 0.0f;
            s_x0[tid] = fminf(fmaxf(x0, 0.0f), 1.0f);
        }
        __syncthreads();
        int half = tid >> 7, c = tid & 127;
        #pragma unroll 8
        for (int rr = 0; rr < 32; rr++) {
            int r = half + rr * 2;
            sH[r * 136 + c] = f2bf(fmaxf(s_x0[r] * w1c + b1c, 0.0f));
        }
        __syncthreads();
        f32x4 acc[4][2];
        #pragma unroll
        for (int s = 0; s < 4; s++) { acc[s][0] = (f32x4){0,0,0,0}; acc[s][1] = (f32x4){0,0,0,0}; }
        #pragma unroll
        for (int kk = 0; kk < 4; kk++) {
            #pragma unroll
            for (int s = 0; s < 4; s++) {
                short8 a = *(const short8*)&sH[(s * 16 + n15) * 136 + kk * 32 + quad * 8];
                acc[s][0] = __builtin_amdgcn_mfma_f32_16x16x32_bf16(a, fW2[kk][0], acc[s][0], 0, 0, 0);
                acc[s][1] = __builtin_amdgcn_mfma_f32_16x16x32_bf16(a, fW2[kk][1], acc[s][1], 0, 0, 0);
            }
        }
        #pragma unroll
        for (int s = 0; s < 4; s++)
            #pragma unroll
            for (int nt = 0; nt < 2; nt++) {
                int col = w * 32 + nt * 16 + n15;
                #pragma unroll
                for (int reg = 0; reg < 4; reg++) {
                    int n = row0 + s * 16 + quad * 4 + reg;
                    if (n < N_NODES)
                        x_out[(long)n * H + col] = f2bf(acc[s][nt][reg] + rb2[nt]);
                }
            }
        __syncthreads();
    }
}

// ---------------- edge MLP: direct-global A, row-assembled scatter stores --
__global__ __launch_bounds__(256) void edge_mlp_mfma(
    const float* __restrict__ attr,
    const int* __restrict__ pos_of,
    const short8* __restrict__ pW1, const float* __restrict__ b1,
    const short8* __restrict__ pW2, const float* __restrict__ b2,
    u16* __restrict__ e_perm)
{
    __shared__ u16 sH[64 * 136];
    __shared__ int sPos[64];
    int tid = threadIdx.x;
    int w = tid >> 6, lane = tid & 63, quad = lane >> 4, n15 = lane & 15;
    short8 fW1[2];
    fW1[0] = pW1[(w * 2 + 0) * 64 + lane];
    fW1[1] = pW1[(w * 2 + 1) * 64 + lane];
    short8 fW2[4][2];
    #pragma unroll
    for (int kk = 0; kk < 4; kk++) {
        fW2[kk][0] = pW2[((w * 4 + kk) * 2 + 0) * 64 + lane];
        fW2[kk][1] = pW2[((w * 4 + kk) * 2 + 1) * 64 + lane];
    }
    float rb1[2] = { b1[w * 32 + n15], b1[w * 32 + 16 + n15] };
    float rb2[2] = { b2[w * 32 + n15], b2[w * 32 + 16 + n15] };
    const int ntile = N_EDGES / 64;   // 9375 exact
    for (int tile = blockIdx.x; tile < ntile; tile += gridDim.x) {
        int row0 = tile * 64;
        // GEMM1: A-fragments direct from attr (quad 0 holds k=0..7, rest zero)
        f32x4 acc[4][2];
        #pragma unroll
        for (int s = 0; s < 4; s++) { acc[s][0] = (f32x4){0,0,0,0}; acc[s][1] = (f32x4){0,0,0,0}; }
        #pragma unroll
        for (int s = 0; s < 4; s++) {
            short8 a = {0,0,0,0,0,0,0,0};
            if (quad == 0) {
                long r = row0 + s * 16 + n15;
                float4 v0 = *(const float4*)&attr[r * ED];
                float4 v1 = *(const float4*)&attr[r * ED + 4];
                a[0] = (short)f2bf(v0.x); a[1] = (short)f2bf(v0.y);
                a[2] = (short)f2bf(v0.z); a[3] = (short)f2bf(v0.w);
                a[4] = (short)f2bf(v1.x); a[5] = (short)f2bf(v1.y);
                a[6] = (short)f2bf(v1.z); a[7] = (short)f2bf(v1.w);
            }
            acc[s][0] = __builtin_amdgcn_mfma_f32_16x16x32_bf16(a, fW1[0], acc[s][0], 0, 0, 0);
            acc[s][1] = __builtin_amdgcn_mfma_f32_16x16x32_bf16(a, fW1[1], acc[s][1], 0, 0, 0);
        }
        __syncthreads();   // prev-tile store reads of sH/sPos complete
        if (tid < 64) sPos[tid] = pos_of[row0 + tid];
        #pragma unroll
        for (int s = 0; s < 4; s++)
            #pragma unroll
            for (int nt = 0; nt < 2; nt++) {
                int col = w * 32 + nt * 16 + n15;
                #pragma unroll
                for (int reg = 0; reg < 4; reg++)
                    sH[(s * 16 + quad * 4 + reg) * 136 + col] =
                        f2bf(fmaxf(acc[s][nt][reg] + rb1[nt], 0.0f));
            }
        __syncthreads();
        // GEMM2 (K=128)
        #pragma unroll
        for (int s = 0; s < 4; s++) { acc[s][0] = (f32x4){0,0,0,0}; acc[s][1] = (f32x4){0,0,0,0}; }
        #pragma unroll
        for (int kk = 0; kk < 4; kk++) {
            #pragma unroll
            for (int s = 0; s < 4; s++) {
                short8 a = *(const short8*)&sH[(s * 16 + n15) * 136 + kk * 32 + quad * 8];
                acc[s][0] = __builtin_amdgcn_mfma_f32_16x16x32_bf16(a, fW2[kk][0], acc[s][0], 0, 0, 0);
                acc[s][1] = __builtin_amdgcn_mfma_f32_16x16x32_bf16(a, fW2[kk][1], acc[s][1], 0, 0, 0);
            }
        }
        __syncthreads();   // all GEMM2 sH reads done
        #pragma unroll
        for (int s = 0; s < 4; s++)
            #pragma unroll
            for (int nt = 0; nt < 2; nt++) {
                int col = w * 32 + nt * 16 + n15;
                #pragma unroll
                for (int reg = 0; reg < 4; reg++)
                    sH[(s * 16 + quad * 4 + reg) * 136 + col] =
                        f2bf(acc[s][nt][reg] + rb2[nt]);
            }
        __syncthreads();
        // coalesced row scatter: 4 rows per instr, 16 B per lane
        #pragma unroll
        for (int it = 0; it < 4; it++) {
            int rr = w * 4 + it * 16 + (lane >> 4);
            long pos = sPos[rr];
            uint4 v = *(const uint4*)&sH[rr * 136 + (lane & 15) * 8];
            *(uint4*)&e_perm[pos * H + (lane & 15) * 8] = v;
        }
    }
}

// ---- aggregate: 2 edges/wave, dwordx2 lanes, e stream sequential ----------
__global__ __launch_bounds__(256) void aggregate_kernel(
    const int* __restrict__ src_list,
    const int* __restrict__ row_ptr,
    const u16* __restrict__ e_perm,
    const u16* __restrict__ x,
    u16* __restrict__ xs_out)
{
    int wave = threadIdx.x >> 6;
    int lane = threadIdx.x & 63;
    int half = lane >> 5;          // which edge of the pair
    int fo   = (lane & 31) * 4;    // 4 columns per lane
    const int ngroups = N_NODES / 4;   // 25000
    for (int g = blockIdx.x; g < ngroups; g += gridDim.x) {
        int n = g * 4 + wave;
        int beg = row_ptr[n];
        int end = row_ptr[n + 1];
        float a0 = 0.0f, a1 = 0.0f, a2 = 0.0f, a3 = 0.0f;
        for (int j0 = beg; j0 < end; j0 += 64) {
            int m = min(64, end - j0);
            int sv = (lane < m) ? src_list[j0 + lane] : 0;
            for (int k = 0; 2 * k < m; k++) {
                int idx = 2 * k + half;
                bool valid = idx < m;
                int src = __shfl(sv, idx);
                long p = j0 + (valid ? idx : 0);
                uint2 ev = *(const uint2*)&e_perm[p * H + fo];
                uint2 xv = *(const uint2*)&x[(long)src * H + fo];
                float m0 = fmaxf(bf2f(xv.x & 0xffff) + bf2f(ev.x & 0xffff), 0.0f);
                float m1 = fmaxf(bf2f(xv.x >> 16)    + bf2f(ev.x >> 16),    0.0f);
                float m2 = fmaxf(bf2f(xv.y & 0xffff) + bf2f(ev.y & 0xffff), 0.0f);
                float m3 = fmaxf(bf2f(xv.y >> 16)    + bf2f(ev.y >> 16),    0.0f);
                if (valid) { a0 += m0; a1 += m1; a2 += m2; a3 += m3; }
            }
        }
        a0 += __shfl_xor(a0, 32);
        a1 += __shfl_xor(a1, 32);
        a2 += __shfl_xor(a2, 32);
        a3 += __shfl_xor(a3, 32);
        uint2 xself = *(const uint2*)&x[(long)n * H + fo];
        float o0 = bf2f(xself.x & 0xffff) + a0;
        float o1 = bf2f(xself.x >> 16)    + a1;
        float o2 = bf2f(xself.y & 0xffff) + a2;
        float o3 = bf2f(xself.y >> 16)    + a3;
        if (half == 0) {
            uint2 o;
            o.x = (u32)f2bf(o0) | ((u32)f2bf(o1) << 16);
            o.y = (u32)f2bf(o2) | ((u32)f2bf(o3) << 16);
            *(uint2*)&xs_out[(long)n * H + fo] = o;
        }
    }
}

// ---------------- conv MLP: direct-global A, LDS only for h1 + out ---------
__global__ __launch_bounds__(256) void conv_mlp_mfma(
    const u16* __restrict__ xs,
    const short8* __restrict__ pW1, const float* __restrict__ b1,
    const short8* __restrict__ pW2, const float* __restrict__ b2,
    u16* __restrict__ x_out)
{
    __shared__ u16 sH[64 * 136];
    int tid = threadIdx.x;
    int w = tid >> 6, lane = tid & 63, quad = lane >> 4, n15 = lane & 15;
    short8 fW1[4][2], fW2[4][2];
    #pragma unroll
    for (int kk = 0; kk < 4; kk++) {
        fW1[kk][0] = pW1[((w * 4 + kk) * 2 + 0) * 64 + lane];
        fW1[kk][1] = pW1[((w * 4 + kk) * 2 + 1) * 64 + lane];
        fW2[kk][0] = pW2[((w * 4 + kk) * 2 + 0) * 64 + lane];
        fW2[kk][1] = pW2[((w * 4 + kk) * 2 + 1) * 64 + lane];
    }
    float rb1[2] = { b1[w * 32 + n15], b1[w * 32 + 16 + n15] };
    float rb2[2] = { b2[w * 32 + n15], b2[w * 32 + 16 + n15] };
    const int ntile = (N_NODES + 63) / 64;
    for (int tile = blockIdx.x; tile < ntile; tile += gridDim.x) {
        int row0 = tile * 64;
        // GEMM1: A-fragments direct from global (16 B per lane, L1-reused)
        f32x4 acc[4][2];
        #pragma unroll
        for (int s = 0; s < 4; s++) { acc[s][0] = (f32x4){0,0,0,0}; acc[s][1] = (f32x4){0,0,0,0}; }
        #pragma unroll
        for (int kk = 0; kk < 4; kk++) {
            #pragma unroll
            for (int s = 0; s < 4; s++) {
                int r = row0 + s * 16 + n15;
                short8 a = {0,0,0,0,0,0,0,0};
                if (r < N_NODES) a = *(const short8*)&xs[(long)r * H + kk * 32 + quad * 8];
                acc[s][0] = __builtin_amdgcn_mfma_f32_16x16x32_bf16(a, fW1[kk][0], acc[s][0], 0, 0, 0);
                acc[s][1] = __builtin_amdgcn_mfma_f32_16x16x32_bf16(a, fW1[kk][1], acc[s][1], 0, 0, 0);
            }
        }
        __syncthreads();   // prev-tile output copy reads of sH complete
        #pragma unroll
        for (int s = 0; s < 4; s++)
            #pragma unroll
            for (int nt = 0; nt < 2; nt++) {
                int col = w * 32 + nt * 16 + n15;
                #pragma unroll
                for (int reg = 0; reg < 4; reg++)
                    sH[(s * 16 + quad * 4 + reg) * 136 + col] =
                        f2bf(fmaxf(acc[s][nt][reg] + rb1[nt], 0.0f));
            }
        __syncthreads();
        // GEMM2
        #pragma unroll
        for (int s = 0; s < 4; s++) { acc[s][0] = (f32x4){0,0,0,0}; acc[s][1] = (f32x4){0,0,0,0}; }
        #pragma unroll
        for (int kk = 0; kk < 4; kk++) {
            #pragma unroll
            for (int s = 0; s < 4; s++) {
                short8 a = *(const short8*)&sH[(s * 16 + n15) * 136 + kk * 32 + quad * 8];
                acc[s][0] = __builtin_amdgcn_mfma_f32_16x16x32_bf16(a, fW2[kk][0], acc[s][0], 0, 0, 0);
                acc[s][1] = __builtin_amdgcn_mfma_f32_16x16x32_bf16(a, fW2[kk][1], acc[s][1], 0, 0, 0);
            }
        }
        __syncthreads();
        #pragma unroll
        for (int s = 0; s < 4; s++)
            #pragma unroll
            for (int nt = 0; nt < 2; nt++) {
                int col = w * 32 + nt * 16 + n15;
                #pragma unroll
                for (int reg = 0; reg < 4; reg++)
                    sH[(s * 16 + quad * 4 + reg) * 136 + col] =
                        f2bf(fmaxf(acc[s][nt][reg] + rb2[nt], 0.0f));
            }
        __syncthreads();
        // fully-coalesced output copy (rows consecutive)
        for (int i = tid; i < 64 * 16; i += 256) {
            int rr = i >> 4, c8 = (i & 15) * 8;
            int n = row0 + rr;
            if (n < N_NODES) {
                uint4 v = *(const uint4*)&sH[rr * 136 + c8];
                *(uint4*)&x_out[(long)n * H + c8] = v;
            }
        }
    }
}

// ---------------- mean-pool (vectorized, segment flush) --------------------
__global__ __launch_bounds__(256) void pool_kernel(
    const u16* __restrict__ x, const int* __restrict__ batch,
    float* __restrict__ sums, float* __restrict__ cnt)
{
    int sg   = threadIdx.x >> 6;
    int lane = threadIdx.x & 63;
    int fo = lane * 2;
    const int nper = (N_NODES + gridDim.x - 1) / gridDim.x;
    int n0 = blockIdx.x * nper;
    int n1 = min(n0 + nper, N_NODES);
    int cur = -1;
    float a0 = 0.0f, a1 = 0.0f, c = 0.0f;
    for (int n = n0 + sg; n < n1; n += 4) {
        int b = batch[n];
        if (b != cur) {
            if (cur >= 0) {
                atomicAdd(&sums[cur * H + fo],     a0);
                atomicAdd(&sums[cur * H + fo + 1], a1);
                if (lane == 0) atomicAdd(&cnt[cur], c);
            }
            a0 = a1 = 0.0f; c = 0.0f; cur = b;
        }
        u32 xv = *(const u32*)&x[(long)n * H + fo];
        a0 += bf2f(xv & 0xffff);
        a1 += bf2f(xv >> 16);
        c += 1.0f;
    }
    if (cur >= 0) {
        atomicAdd(&sums[cur * H + fo],     a0);
        atomicAdd(&sums[cur * H + fo + 1], a1);
        if (lane == 0) atomicAdd(&cnt[cur], c);
    }
}

// ---------------- regressor ------------------------------------------------
__global__ __launch_bounds__(128) void regressor_kernel(
    const float* __restrict__ sums, const float* __restrict__ cnt,
    const float* __restrict__ depth,
    const float* __restrict__ w1, const float* __restrict__ b1,
    const float* __restrict__ w2, const float* __restrict__ b2,
    float* __restrict__ out)
{
    __shared__ float s_mean[H];
    __shared__ float s_red[2];
    int b = blockIdx.x;
    int j = threadIdx.x;
    float c = fmaxf(cnt[b], 1.0f);
    s_mean[j] = sums[b * H + j] / c;
    __syncthreads();
    float h = b1[j];
    #pragma unroll 8
    for (int k = 0; k < H; k++) h += s_mean[k] * w1[k * H + j];
    h += depth[b] * w1[H * H + j];
    h = fmaxf(h, 0.0f);
    float p = h * w2[j];
    #pragma unroll
    for (int off = 32; off >= 1; off >>= 1) p += __shfl_down(p, off, 64);
    if ((j & 63) == 0) s_red[j >> 6] = p;
    __syncthreads();
    if (j == 0) out[b] = s_red[0] + s_red[1] + b2[0];
}

extern "C" void kernel_launch(void* const* d_in, const int* in_sizes, int n_in,
                              void* d_out, int out_size, void* d_ws, size_t ws_size,
                              hipStream_t stream)
{
    const int*   ids   = (const int*)  d_in[0];
    const int*   eidx  = (const int*)  d_in[1];
    const float* eattr = (const float*)d_in[2];
    const int*   batch = (const int*)  d_in[3];
    const float* depth = (const float*)d_in[4];
    const float* id_w1 = (const float*)d_in[5];
    const float* id_b1 = (const float*)d_in[6];
    const float* id_w2 = (const float*)d_in[7];
    const float* id_b2 = (const float*)d_in[8];
    const float* ed_w1 = (const float*)d_in[9];
    const float* ed_b1 = (const float*)d_in[10];
    const float* ed_w2 = (const float*)d_in[11];
    const float* ed_b2 = (const float*)d_in[12];
    const float* c1_w1 = (const float*)d_in[13];
    const float* c1_b1 = (const float*)d_in[14];
    const float* c1_w2 = (const float*)d_in[15];
    const float* c1_b2 = (const float*)d_in[16];
    const float* c2_w1 = (const float*)d_in[17];
    const float* c2_b1 = (const float*)d_in[18];
    const float* c2_w2 = (const float*)d_in[19];
    const float* c2_b2 = (const float*)d_in[20];
    const float* rg_w1 = (const float*)d_in[21];
    const float* rg_b1 = (const float*)d_in[22];
    const float* rg_w2 = (const float*)d_in[23];
    const float* rg_b2 = (const float*)d_in[24];

    char* ws = (char*)d_ws;
    u16*   e_buf    = (u16*)  (ws);                      // 153,600,000 B (CSR order)
    u16*   x_buf    = (u16*)  (ws + 153600000);          //  25,600,000 B
    u16*   xs_buf   = (u16*)  (ws + 179200000);          //  25,600,000 B
    float* sums_buf = (float*)(ws + 204800000);          //     262,144 B
    float* cnt_buf  = (float*)(ws + 205062144);          //       2,048 B
    int*   counts   = (int*)  (ws + 205064192);          //     401,408 B
    int*   chunk_sc = (int*)  (ws + 205465600);          //     401,408 B
    int*   bsum_raw = (int*)  (ws + 205867008);          //         512 B
    int*   bsum_sc  = (int*)  (ws + 205867520);          //         512 B
    int*   src_list = (int*)  (ws + 205868032);          //   2,400,000 B
    int*   pos_of   = (int*)  (ws + 208268032);          //   2,400,000 B
    short8* ed_w1p  = (short8*)(ws + 210668032);         //       8,192 B
    short8* ed_w2p  = (short8*)(ws + 210676224);         //      32,768 B
    short8* c1_w1p  = (short8*)(ws + 210708992);
    short8* c1_w2p  = (short8*)(ws + 210741760);
    short8* c2_w1p  = (short8*)(ws + 210774528);
    short8* c2_w2p  = (short8*)(ws + 210807296);
    short8* id_w2p  = (short8*)(ws + 210840064);
    int*   row_ptr  = (int*)  (ws + 210872832);          //     400,004 B

    pack_all_kernel<<<50, 256, 0, stream>>>(
        ed_w1, ed_w2, c1_w1, c1_w2, c2_w1, c2_w2, id_w2,
        ed_w1p, ed_w2p, c1_w1p, c1_w2p, c2_w1p, c2_w2p, id_w2p);

    // CSR build
    hipMemsetAsync(counts, 0, 401408, stream);
    hist_kernel <<<(N_EDGES + 255) / 256, 256, 0, stream>>>(eidx, counts);
    scan1_kernel<<<N_CHUNKS, SCAN_CHUNK, 0, stream>>>(counts, chunk_sc, bsum_raw);
    scan2_kernel<<<1, 128, 0, stream>>>(bsum_raw, bsum_sc);
    rowptr_kernel<<<(N_NODES + 256) / 256, 256, 0, stream>>>(chunk_sc, bsum_sc, row_ptr);
    fill_kernel <<<(N_EDGES + 255) / 256, 256, 0, stream>>>(eidx, chunk_sc, bsum_sc,
                                                            counts, src_list, pos_of);

    // front-end
    node_mlp_mfma<<<768, 256, 0, stream>>>(ids, id_w1, id_b1, id_w2p, id_b2, x_buf);
    edge_mlp_mfma<<<2048, 256, 0, stream>>>(eattr, pos_of, ed_w1p, ed_b1, ed_w2p, ed_b2, e_buf);

    // conv 1
    aggregate_kernel<<<8192, 256, 0, stream>>>(src_list, row_ptr, e_buf, x_buf, xs_buf);
    conv_mlp_mfma<<<1563, 256, 0, stream>>>(xs_buf, c1_w1p, c1_b1, c1_w2p, c1_b2, x_buf);

    // conv 2
    aggregate_kernel<<<8192, 256, 0, stream>>>(src_list, row_ptr, e_buf, x_buf, xs_buf);
    conv_mlp_mfma<<<1563, 256, 0, stream>>>(xs_buf, c2_w1p, c2_b1, c2_w2p, c2_b2, x_buf);

    // pooling + regressor
    hipMemsetAsync(sums_buf, 0, (size_t)(NB * H + NB) * 4, stream);
    pool_kernel<<<2048, 256, 0, stream>>>(x_buf, batch, sums_buf, cnt_buf);
    regressor_kernel<<<NB, 128, 0, stream>>>(sums_buf, cnt_buf, depth,
                                             rg_w1, rg_b1, rg_w2, rg_b2, (float*)d_out);
}

// Round 8
// 442.613 us; speedup vs baseline: 1.0587x; 1.0587x over previous
//
#include <hip/hip_runtime.h>
#include <hip/hip_bf16.h>

#define N_NODES 100000
#define N_EDGES 600000
#define NB      512
#define H       128
#define ED      8
#define SCAN_CHUNK 1024
#define N_CHUNKS   98   // 98*1024 = 100352 >= N_NODES+1

typedef __attribute__((ext_vector_type(8))) short short8;
typedef __attribute__((ext_vector_type(4))) float f32x4;
typedef unsigned short u16;
typedef unsigned int   u32;

static __device__ __forceinline__ u16 f2bf(float f) {
    u32 u = __float_as_uint(f);
    u32 r = u + 0x7fffu + ((u >> 16) & 1u);
    return (u16)(r >> 16);
}
static __device__ __forceinline__ float bf2f(u32 h) {
    return __uint_as_float(h << 16);
}

// ---- weight pack (ALL matrices in one launch) -----------------------------
__global__ __launch_bounds__(256) void pack_all_kernel(
    const float* __restrict__ W0, const float* __restrict__ W1,
    const float* __restrict__ W2, const float* __restrict__ W3,
    const float* __restrict__ W4, const float* __restrict__ W5,
    const float* __restrict__ W6,
    short8* __restrict__ O0, short8* __restrict__ O1,
    short8* __restrict__ O2, short8* __restrict__ O3,
    short8* __restrict__ O4, short8* __restrict__ O5,
    short8* __restrict__ O6)
{
    int gid = blockIdx.x * 256 + threadIdx.x;
    const int total = 512 + 6 * 2048;
    if (gid >= total) return;
    const float* W; short8* O; int Krows, kkmax, slot;
    if (gid < 512) { W = W0; O = O0; Krows = ED; kkmax = 1; slot = gid; }
    else {
        int m = (gid - 512) / 2048;
        slot = (gid - 512) % 2048;
        Krows = H; kkmax = 4;
        switch (m) {
            case 0: W = W1; O = O1; break;
            case 1: W = W2; O = O2; break;
            case 2: W = W3; O = O3; break;
            case 3: W = W4; O = O4; break;
            case 4: W = W5; O = O5; break;
            default: W = W6; O = O6; break;
        }
    }
    int lane = slot & 63;
    int t = slot >> 6;
    int nt = t & 1; t >>= 1;
    int kk = t % kkmax;
    int w  = t / kkmax;
    int quad = lane >> 4, n15 = lane & 15;
    int n = w * 32 + nt * 16 + n15;
    short8 v;
    #pragma unroll
    for (int j = 0; j < 8; j++) {
        int k = kk * 32 + quad * 8 + j;
        v[j] = (k < Krows) ? (short)f2bf(W[k * H + n]) : (short)0;
    }
    O[slot] = v;
}

// ---------------- CSR build ------------------------------------------------
__global__ __launch_bounds__(256) void hist_kernel(
    const int* __restrict__ edge_index, int* __restrict__ counts)
{
    int e = blockIdx.x * 256 + threadIdx.x;
    if (e < N_EDGES) atomicAdd(&counts[edge_index[N_EDGES + e]], 1);
}

__global__ __launch_bounds__(SCAN_CHUNK) void scan1_kernel(
    const int* __restrict__ counts, int* __restrict__ chunk_scan,
    int* __restrict__ bsum_raw)
{
    __shared__ int s[SCAN_CHUNK];
    int tid = threadIdx.x;
    int gid = blockIdx.x * SCAN_CHUNK + tid;
    int v = counts[gid];
    s[tid] = v;
    __syncthreads();
    #pragma unroll
    for (int off = 1; off < SCAN_CHUNK; off <<= 1) {
        int t = (tid >= off) ? s[tid - off] : 0;
        __syncthreads();
        s[tid] += t;
        __syncthreads();
    }
    chunk_scan[gid] = s[tid] - v;
    if (tid == SCAN_CHUNK - 1) bsum_raw[blockIdx.x] = s[tid];
}

__global__ __launch_bounds__(128) void scan2_kernel(
    const int* __restrict__ bsum_raw, int* __restrict__ bsum_scan)
{
    __shared__ int s[128];
    int tid = threadIdx.x;
    int v = (tid < N_CHUNKS) ? bsum_raw[tid] : 0;
    s[tid] = v;
    __syncthreads();
    #pragma unroll
    for (int off = 1; off < 128; off <<= 1) {
        int t = (tid >= off) ? s[tid - off] : 0;
        __syncthreads();
        s[tid] += t;
        __syncthreads();
    }
    bsum_scan[tid] = s[tid] - v;
}

__global__ __launch_bounds__(256) void rowptr_kernel(
    const int* __restrict__ chunk_scan, const int* __restrict__ bsum_scan,
    int* __restrict__ row_ptr)
{
    int gid = blockIdx.x * 256 + threadIdx.x;
    if (gid <= N_NODES) row_ptr[gid] = chunk_scan[gid] + bsum_scan[gid >> 10];
}

__global__ __launch_bounds__(256) void fill_kernel(
    const int* __restrict__ edge_index,
    const int* __restrict__ chunk_scan, const int* __restrict__ bsum_scan,
    int* __restrict__ counts, int* __restrict__ src_list,
    int* __restrict__ pos_of)
{
    int e = blockIdx.x * 256 + threadIdx.x;
    if (e >= N_EDGES) return;
    int src = edge_index[e];
    int dst = edge_index[N_EDGES + e];
    int slot = atomicAdd(&counts[dst], -1) - 1;
    int pos = chunk_scan[dst] + bsum_scan[dst >> 10] + slot;
    src_list[pos] = src;
    pos_of[e] = pos;
}

// ---------------- node MLP (MFMA layer2): x bf16 [N,H] ---------------------
__global__ __launch_bounds__(256) void node_mlp_mfma(
    const int* __restrict__ ids,
    const float* __restrict__ w1, const float* __restrict__ b1,
    const short8* __restrict__ pW2, const float* __restrict__ b2,
    u16* __restrict__ x_out)
{
    __shared__ u16 sH[64 * 136];
    __shared__ float s_x0[64];
    int tid = threadIdx.x;
    int w = tid >> 6, lane = tid & 63, quad = lane >> 4, n15 = lane & 15;
    short8 fW2[4][2];
    #pragma unroll
    for (int kk = 0; kk < 4; kk++) {
        fW2[kk][0] = pW2[((w * 4 + kk) * 2 + 0) * 64 + lane];
        fW2[kk][1] = pW2[((w * 4 + kk) * 2 + 1) * 64 + lane];
    }
    float rb2[2] = { b2[w * 32 + n15], b2[w * 32 + 16 + n15] };
    float w1c = w1[tid & 127], b1c = b1[tid & 127];
    const int ntile = (N_NODES + 63) / 64;
    for (int tile = blockIdx.x; tile < ntile; tile += gridDim.x) {
        int row0 = tile * 64;
        if (tid < 64) {
            int n = row0 + tid;
            float x0 = (n < N_NODES) ? (float)ids[n] / 281474976710655.0f : 0.0f;
            s_x0[tid] = fminf(fmaxf(x0, 0.0f), 1.0f);
        }
        __syncthreads();
        int half = tid >> 7, c = tid & 127;
        #pragma unroll 8
        for (int rr = 0; rr < 32; rr++) {
            int r = half + rr * 2;
            sH[r * 136 + c] = f2bf(fmaxf(s_x0[r] * w1c + b1c, 0.0f));
        }
        __syncthreads();
        f32x4 acc[4][2];
        #pragma unroll
        for (int s = 0; s < 4; s++) { acc[s][0] = (f32x4){0,0,0,0}; acc[s][1] = (f32x4){0,0,0,0}; }
        #pragma unroll
        for (int kk = 0; kk < 4; kk++) {
            #pragma unroll
            for (int s = 0; s < 4; s++) {
                short8 a = *(const short8*)&sH[(s * 16 + n15) * 136 + kk * 32 + quad * 8];
                acc[s][0] = __builtin_amdgcn_mfma_f32_16x16x32_bf16(a, fW2[kk][0], acc[s][0], 0, 0, 0);
                acc[s][1] = __builtin_amdgcn_mfma_f32_16x16x32_bf16(a, fW2[kk][1], acc[s][1], 0, 0, 0);
            }
        }
        #pragma unroll
        for (int s = 0; s < 4; s++)
            #pragma unroll
            for (int nt = 0; nt < 2; nt++) {
                int col = w * 32 + nt * 16 + n15;
                #pragma unroll
                for (int reg = 0; reg < 4; reg++) {
                    int n = row0 + s * 16 + quad * 4 + reg;
                    if (n < N_NODES)
                        x_out[(long)n * H + col] = f2bf(acc[s][nt][reg] + rb2[nt]);
                }
            }
        __syncthreads();
    }
}

// ---------------- edge MLP (R6 structure): LDS-staged A, scatter epilogue --
__global__ __launch_bounds__(256) void edge_mlp_mfma(
    const float* __restrict__ attr,
    const int* __restrict__ pos_of,
    const short8* __restrict__ pW1, const float* __restrict__ b1,
    const short8* __restrict__ pW2, const float* __restrict__ b2,
    u16* __restrict__ e_perm)
{
    __shared__ u16 sA[64 * 40];
    __shared__ u16 sH[64 * 136];
    __shared__ int sPos[64];
    int tid = threadIdx.x;
    int w = tid >> 6, lane = tid & 63, quad = lane >> 4, n15 = lane & 15;
    short8 fW1[2];
    fW1[0] = pW1[(w * 2 + 0) * 64 + lane];
    fW1[1] = pW1[(w * 2 + 1) * 64 + lane];
    short8 fW2[4][2];
    #pragma unroll
    for (int kk = 0; kk < 4; kk++) {
        fW2[kk][0] = pW2[((w * 4 + kk) * 2 + 0) * 64 + lane];
        fW2[kk][1] = pW2[((w * 4 + kk) * 2 + 1) * 64 + lane];
    }
    float rb1[2] = { b1[w * 32 + n15], b1[w * 32 + 16 + n15] };
    float rb2[2] = { b2[w * 32 + n15], b2[w * 32 + 16 + n15] };
    // zero-fill sA cols 8..31 ONCE (never overwritten by the tile loop)
    for (int idx = tid; idx < 64 * 3; idx += 256) {
        int r = idx / 3, c8 = 8 + (idx % 3) * 8;
        *(uint4*)&sA[r * 40 + c8] = make_uint4(0, 0, 0, 0);
    }
    const int ntile = N_EDGES / 64;   // 9375 exact
    for (int tile = blockIdx.x; tile < ntile; tile += gridDim.x) {
        int row0 = tile * 64;
        if (tid < 64) sPos[tid] = pos_of[row0 + tid];
        else if (tid < 192) {
            int t2 = tid - 64;
            int r = t2 >> 1, c4 = (t2 & 1) * 4;
            float4 v = *(const float4*)&attr[(long)(row0 + r) * ED + c4];
            ushort4 o;
            o.x = f2bf(v.x); o.y = f2bf(v.y); o.z = f2bf(v.z); o.w = f2bf(v.w);
            *(ushort4*)&sA[r * 40 + c4] = o;
        }
        __syncthreads();
        // GEMM1 (K=32, one step)
        f32x4 acc[4][2];
        #pragma unroll
        for (int s = 0; s < 4; s++) { acc[s][0] = (f32x4){0,0,0,0}; acc[s][1] = (f32x4){0,0,0,0}; }
        #pragma unroll
        for (int s = 0; s < 4; s++) {
            short8 a = *(const short8*)&sA[(s * 16 + n15) * 40 + quad * 8];
            acc[s][0] = __builtin_amdgcn_mfma_f32_16x16x32_bf16(a, fW1[0], acc[s][0], 0, 0, 0);
            acc[s][1] = __builtin_amdgcn_mfma_f32_16x16x32_bf16(a, fW1[1], acc[s][1], 0, 0, 0);
        }
        #pragma unroll
        for (int s = 0; s < 4; s++)
            #pragma unroll
            for (int nt = 0; nt < 2; nt++) {
                int col = w * 32 + nt * 16 + n15;
                #pragma unroll
                for (int reg = 0; reg < 4; reg++)
                    sH[(s * 16 + quad * 4 + reg) * 136 + col] =
                        f2bf(fmaxf(acc[s][nt][reg] + rb1[nt], 0.0f));
            }
        __syncthreads();
        // GEMM2 (K=128)
        #pragma unroll
        for (int s = 0; s < 4; s++) { acc[s][0] = (f32x4){0,0,0,0}; acc[s][1] = (f32x4){0,0,0,0}; }
        #pragma unroll
        for (int kk = 0; kk < 4; kk++) {
            #pragma unroll
            for (int s = 0; s < 4; s++) {
                short8 a = *(const short8*)&sH[(s * 16 + n15) * 136 + kk * 32 + quad * 8];
                acc[s][0] = __builtin_amdgcn_mfma_f32_16x16x32_bf16(a, fW2[kk][0], acc[s][0], 0, 0, 0);
                acc[s][1] = __builtin_amdgcn_mfma_f32_16x16x32_bf16(a, fW2[kk][1], acc[s][1], 0, 0, 0);
            }
        }
        #pragma unroll
        for (int s = 0; s < 4; s++)
            #pragma unroll
            for (int nt = 0; nt < 2; nt++) {
                int col = w * 32 + nt * 16 + n15;
                #pragma unroll
                for (int reg = 0; reg < 4; reg++) {
                    long r = sPos[s * 16 + quad * 4 + reg];
                    e_perm[r * H + col] = f2bf(acc[s][nt][reg] + rb2[nt]);
                }
            }
        __syncthreads();
    }
}

// ---- aggregate: batch-issue 8 edge loads per iter (latency hiding) --------
__global__ __launch_bounds__(256) void aggregate_kernel(
    const int* __restrict__ src_list,
    const int* __restrict__ row_ptr,
    const u16* __restrict__ e_perm,
    const u16* __restrict__ x,
    u16* __restrict__ xs_out)
{
    int wave = threadIdx.x >> 6;
    int lane = threadIdx.x & 63;
    int half = lane >> 5;          // which edge of each pair
    int fo   = (lane & 31) * 4;    // 4 columns per lane
    const int ngroups = N_NODES / 4;   // 25000
    for (int g = blockIdx.x; g < ngroups; g += gridDim.x) {
        int n = g * 4 + wave;
        int beg = row_ptr[n];
        int end = row_ptr[n + 1];
        float a0 = 0.0f, a1 = 0.0f, a2 = 0.0f, a3 = 0.0f;
        for (int j0 = beg; j0 < end; j0 += 8) {
            int m = min(8, end - j0);
            int sv = (lane < m) ? src_list[j0 + lane] : 0;
            uint2 ev[4], xv[4];
            bool val[4];
            #pragma unroll
            for (int k = 0; k < 4; k++) {           // 8 loads issued together
                int idx = 2 * k + half;
                val[k] = idx < m;
                int src = __shfl(sv, idx);
                long p = j0 + (val[k] ? idx : 0);
                ev[k] = *(const uint2*)&e_perm[p * H + fo];
                xv[k] = *(const uint2*)&x[(long)src * H + fo];
            }
            #pragma unroll
            for (int k = 0; k < 4; k++) {
                float m0 = fmaxf(bf2f(xv[k].x & 0xffff) + bf2f(ev[k].x & 0xffff), 0.0f);
                float m1 = fmaxf(bf2f(xv[k].x >> 16)    + bf2f(ev[k].x >> 16),    0.0f);
                float m2 = fmaxf(bf2f(xv[k].y & 0xffff) + bf2f(ev[k].y & 0xffff), 0.0f);
                float m3 = fmaxf(bf2f(xv[k].y >> 16)    + bf2f(ev[k].y >> 16),    0.0f);
                if (val[k]) { a0 += m0; a1 += m1; a2 += m2; a3 += m3; }
            }
        }
        a0 += __shfl_xor(a0, 32);
        a1 += __shfl_xor(a1, 32);
        a2 += __shfl_xor(a2, 32);
        a3 += __shfl_xor(a3, 32);
        uint2 xself = *(const uint2*)&x[(long)n * H + fo];
        float o0 = bf2f(xself.x & 0xffff) + a0;
        float o1 = bf2f(xself.x >> 16)    + a1;
        float o2 = bf2f(xself.y & 0xffff) + a2;
        float o3 = bf2f(xself.y >> 16)    + a3;
        if (half == 0) {
            uint2 o;
            o.x = (u32)f2bf(o0) | ((u32)f2bf(o1) << 16);
            o.y = (u32)f2bf(o2) | ((u32)f2bf(o3) << 16);
            *(uint2*)&xs_out[(long)n * H + fo] = o;
        }
    }
}

// ---------------- conv MLP: direct-global A, LDS only for h1 + out ---------
__global__ __launch_bounds__(256) void conv_mlp_mfma(
    const u16* __restrict__ xs,
    const short8* __restrict__ pW1, const float* __restrict__ b1,
    const short8* __restrict__ pW2, const float* __restrict__ b2,
    u16* __restrict__ x_out)
{
    __shared__ u16 sH[64 * 136];
    int tid = threadIdx.x;
    int w = tid >> 6, lane = tid & 63, quad = lane >> 4, n15 = lane & 15;
    short8 fW1[4][2], fW2[4][2];
    #pragma unroll
    for (int kk = 0; kk < 4; kk++) {
        fW1[kk][0] = pW1[((w * 4 + kk) * 2 + 0) * 64 + lane];
        fW1[kk][1] = pW1[((w * 4 + kk) * 2 + 1) * 64 + lane];
        fW2[kk][0] = pW2[((w * 4 + kk) * 2 + 0) * 64 + lane];
        fW2[kk][1] = pW2[((w * 4 + kk) * 2 + 1) * 64 + lane];
    }
    float rb1[2] = { b1[w * 32 + n15], b1[w * 32 + 16 + n15] };
    float rb2[2] = { b2[w * 32 + n15], b2[w * 32 + 16 + n15] };
    const int ntile = (N_NODES + 63) / 64;
    for (int tile = blockIdx.x; tile < ntile; tile += gridDim.x) {
        int row0 = tile * 64;
        f32x4 acc[4][2];
        #pragma unroll
        for (int s = 0; s < 4; s++) { acc[s][0] = (f32x4){0,0,0,0}; acc[s][1] = (f32x4){0,0,0,0}; }
        #pragma unroll
        for (int kk = 0; kk < 4; kk++) {
            #pragma unroll
            for (int s = 0; s < 4; s++) {
                int r = row0 + s * 16 + n15;
                short8 a = {0,0,0,0,0,0,0,0};
                if (r < N_NODES) a = *(const short8*)&xs[(long)r * H + kk * 32 + quad * 8];
                acc[s][0] = __builtin_amdgcn_mfma_f32_16x16x32_bf16(a, fW1[kk][0], acc[s][0], 0, 0, 0);
                acc[s][1] = __builtin_amdgcn_mfma_f32_16x16x32_bf16(a, fW1[kk][1], acc[s][1], 0, 0, 0);
            }
        }
        __syncthreads();   // prev-tile output copy reads of sH complete
        #pragma unroll
        for (int s = 0; s < 4; s++)
            #pragma unroll
            for (int nt = 0; nt < 2; nt++) {
                int col = w * 32 + nt * 16 + n15;
                #pragma unroll
                for (int reg = 0; reg < 4; reg++)
                    sH[(s * 16 + quad * 4 + reg) * 136 + col] =
                        f2bf(fmaxf(acc[s][nt][reg] + rb1[nt], 0.0f));
            }
        __syncthreads();
        #pragma unroll
        for (int s = 0; s < 4; s++) { acc[s][0] = (f32x4){0,0,0,0}; acc[s][1] = (f32x4){0,0,0,0}; }
        #pragma unroll
        for (int kk = 0; kk < 4; kk++) {
            #pragma unroll
            for (int s = 0; s < 4; s++) {
                short8 a = *(const short8*)&sH[(s * 16 + n15) * 136 + kk * 32 + quad * 8];
                acc[s][0] = __builtin_amdgcn_mfma_f32_16x16x32_bf16(a, fW2[kk][0], acc[s][0], 0, 0, 0);
                acc[s][1] = __builtin_amdgcn_mfma_f32_16x16x32_bf16(a, fW2[kk][1], acc[s][1], 0, 0, 0);
            }
        }
        __syncthreads();
        #pragma unroll
        for (int s = 0; s < 4; s++)
            #pragma unroll
            for (int nt = 0; nt < 2; nt++) {
                int col = w * 32 + nt * 16 + n15;
                #pragma unroll
                for (int reg = 0; reg < 4; reg++)
                    sH[(s * 16 + quad * 4 + reg) * 136 + col] =
                        f2bf(fmaxf(acc[s][nt][reg] + rb2[nt], 0.0f));
            }
        __syncthreads();
        for (int i = tid; i < 64 * 16; i += 256) {
            int rr = i >> 4, c8 = (i & 15) * 8;
            int n = row0 + rr;
            if (n < N_NODES) {
                uint4 v = *(const uint4*)&sH[rr * 136 + c8];
                *(uint4*)&x_out[(long)n * H + c8] = v;
            }
        }
    }
}

// ---------------- mean-pool (vectorized, segment flush) --------------------
__global__ __launch_bounds__(256) void pool_kernel(
    const u16* __restrict__ x, const int* __restrict__ batch,
    float* __restrict__ sums, float* __restrict__ cnt)
{
    int sg   = threadIdx.x >> 6;
    int lane = threadIdx.x & 63;
    int fo = lane * 2;
    const int nper = (N_NODES + gridDim.x - 1) / gridDim.x;
    int n0 = blockIdx.x * nper;
    int n1 = min(n0 + nper, N_NODES);
    int cur = -1;
    float a0 = 0.0f, a1 = 0.0f, c = 0.0f;
    for (int n = n0 + sg; n < n1; n += 4) {
        int b = batch[n];
        if (b != cur) {
            if (cur >= 0) {
                atomicAdd(&sums[cur * H + fo],     a0);
                atomicAdd(&sums[cur * H + fo + 1], a1);
                if (lane == 0) atomicAdd(&cnt[cur], c);
            }
            a0 = a1 = 0.0f; c = 0.0f; cur = b;
        }
        u32 xv = *(const u32*)&x[(long)n * H + fo];
        a0 += bf2f(xv & 0xffff);
        a1 += bf2f(xv >> 16);
        c += 1.0f;
    }
    if (cur >= 0) {
        atomicAdd(&sums[cur * H + fo],     a0);
        atomicAdd(&sums[cur * H + fo + 1], a1);
        if (lane == 0) atomicAdd(&cnt[cur], c);
    }
}

// ---------------- regressor ------------------------------------------------
__global__ __launch_bounds__(128) void regressor_kernel(
    const float* __restrict__ sums, const float* __restrict__ cnt,
    const float* __restrict__ depth,
    const float* __restrict__ w1, const float* __restrict__ b1,
    const float* __restrict__ w2, const float* __restrict__ b2,
    float* __restrict__ out)
{
    __shared__ float s_mean[H];
    __shared__ float s_red[2];
    int b = blockIdx.x;
    int j = threadIdx.x;
    float c = fmaxf(cnt[b], 1.0f);
    s_mean[j] = sums[b * H + j] / c;
    __syncthreads();
    float h = b1[j];
    #pragma unroll 8
    for (int k = 0; k < H; k++) h += s_mean[k] * w1[k * H + j];
    h += depth[b] * w1[H * H + j];
    h = fmaxf(h, 0.0f);
    float p = h * w2[j];
    #pragma unroll
    for (int off = 32; off >= 1; off >>= 1) p += __shfl_down(p, off, 64);
    if ((j & 63) == 0) s_red[j >> 6] = p;
    __syncthreads();
    if (j == 0) out[b] = s_red[0] + s_red[1] + b2[0];
}

extern "C" void kernel_launch(void* const* d_in, const int* in_sizes, int n_in,
                              void* d_out, int out_size, void* d_ws, size_t ws_size,
                              hipStream_t stream)
{
    const int*   ids   = (const int*)  d_in[0];
    const int*   eidx  = (const int*)  d_in[1];
    const float* eattr = (const float*)d_in[2];
    const int*   batch = (const int*)  d_in[3];
    const float* depth = (const float*)d_in[4];
    const float* id_w1 = (const float*)d_in[5];
    const float* id_b1 = (const float*)d_in[6];
    const float* id_w2 = (const float*)d_in[7];
    const float* id_b2 = (const float*)d_in[8];
    const float* ed_w1 = (const float*)d_in[9];
    const float* ed_b1 = (const float*)d_in[10];
    const float* ed_w2 = (const float*)d_in[11];
    const float* ed_b2 = (const float*)d_in[12];
    const float* c1_w1 = (const float*)d_in[13];
    const float* c1_b1 = (const float*)d_in[14];
    const float* c1_w2 = (const float*)d_in[15];
    const float* c1_b2 = (const float*)d_in[16];
    const float* c2_w1 = (const float*)d_in[17];
    const float* c2_b1 = (const float*)d_in[18];
    const float* c2_w2 = (const float*)d_in[19];
    const float* c2_b2 = (const float*)d_in[20];
    const float* rg_w1 = (const float*)d_in[21];
    const float* rg_b1 = (const float*)d_in[22];
    const float* rg_w2 = (const float*)d_in[23];
    const float* rg_b2 = (const float*)d_in[24];

    char* ws = (char*)d_ws;
    u16*   e_buf    = (u16*)  (ws);                      // 153,600,000 B (CSR order)
    u16*   x_buf    = (u16*)  (ws + 153600000);          //  25,600,000 B
    u16*   xs_buf   = (u16*)  (ws + 179200000);          //  25,600,000 B
    float* sums_buf = (float*)(ws + 204800000);          //     262,144 B
    float* cnt_buf  = (float*)(ws + 205062144);          //       2,048 B
    int*   counts   = (int*)  (ws + 205064192);          //     401,408 B
    int*   chunk_sc = (int*)  (ws + 205465600);          //     401,408 B
    int*   bsum_raw = (int*)  (ws + 205867008);          //         512 B
    int*   bsum_sc  = (int*)  (ws + 205867520);          //         512 B
    int*   src_list = (int*)  (ws + 205868032);          //   2,400,000 B
    int*   pos_of   = (int*)  (ws + 208268032);          //   2,400,000 B
    short8* ed_w1p  = (short8*)(ws + 210668032);         //       8,192 B
    short8* ed_w2p  = (short8*)(ws + 210676224);         //      32,768 B
    short8* c1_w1p  = (short8*)(ws + 210708992);
    short8* c1_w2p  = (short8*)(ws + 210741760);
    short8* c2_w1p  = (short8*)(ws + 210774528);
    short8* c2_w2p  = (short8*)(ws + 210807296);
    short8* id_w2p  = (short8*)(ws + 210840064);
    int*   row_ptr  = (int*)  (ws + 210872832);          //     400,004 B

    pack_all_kernel<<<50, 256, 0, stream>>>(
        ed_w1, ed_w2, c1_w1, c1_w2, c2_w1, c2_w2, id_w2,
        ed_w1p, ed_w2p, c1_w1p, c1_w2p, c2_w1p, c2_w2p, id_w2p);

    // CSR build
    hipMemsetAsync(counts, 0, 401408, stream);
    hist_kernel <<<(N_EDGES + 255) / 256, 256, 0, stream>>>(eidx, counts);
    scan1_kernel<<<N_CHUNKS, SCAN_CHUNK, 0, stream>>>(counts, chunk_sc, bsum_raw);
    scan2_kernel<<<1, 128, 0, stream>>>(bsum_raw, bsum_sc);
    rowptr_kernel<<<(N_NODES + 256) / 256, 256, 0, stream>>>(chunk_sc, bsum_sc, row_ptr);
    fill_kernel <<<(N_EDGES + 255) / 256, 256, 0, stream>>>(eidx, chunk_sc, bsum_sc,
                                                            counts, src_list, pos_of);

    // front-end
    node_mlp_mfma<<<768, 256, 0, stream>>>(ids, id_w1, id_b1, id_w2p, id_b2, x_buf);
    edge_mlp_mfma<<<3125, 256, 0, stream>>>(eattr, pos_of, ed_w1p, ed_b1, ed_w2p, ed_b2, e_buf);

    // conv 1
    aggregate_kernel<<<8192, 256, 0, stream>>>(src_list, row_ptr, e_buf, x_buf, xs_buf);
    conv_mlp_mfma<<<1563, 256, 0, stream>>>(xs_buf, c1_w1p, c1_b1, c1_w2p, c1_b2, x_buf);

    // conv 2
    aggregate_kernel<<<8192, 256, 0, stream>>>(src_list, row_ptr, e_buf, x_buf, xs_buf);
    conv_mlp_mfma<<<1563, 256, 0, stream>>>(xs_buf, c2_w1p, c2_b1, c2_w2p, c2_b2, x_buf);

    // pooling + regressor
    hipMemsetAsync(sums_buf, 0, (size_t)(NB * H + NB) * 4, stream);
    pool_kernel<<<2048, 256, 0, stream>>>(x_buf, batch, sums_buf, cnt_buf);
    regressor_kernel<<<NB, 128, 0, stream>>>(sums_buf, cnt_buf, depth,
                                             rg_w1, rg_b1, rg_w2, rg_b2, (float*)d_out);
}